// Round 1
// baseline (1874.422 us; speedup 1.0000x reference)
//
#include <hip/hip_runtime.h>
#include <hip/hip_bf16.h>

#define B_ 8
#define L_ 2048
#define D_ 512
#define Y_ 8921

typedef __bf16 bf16;
typedef __attribute__((ext_vector_type(8))) __bf16 bf16x8;
typedef __attribute__((ext_vector_type(4))) __bf16 bf16x4;
typedef __attribute__((ext_vector_type(4))) float f32x4;

#define MFMA16(a,b,c) __builtin_amdgcn_mfma_f32_16x16x32_bf16((a),(b),(c),0,0,0)

// d_out offsets (in floats): y[B*Y], loss[1], alpha[B*Y*L], m[B*Y*D]
#define OFF_LOSS  71368ull
#define OFF_ALPHA 71369ull
#define OFF_M     146233033ull

// workspace offsets (bytes)
#define WS_XB 0ull           // x bf16   [B][L][D]   16,777,216 B
#define WS_XT 16777216ull    // x^T bf16 [B][D][L]   16,777,216 B
#define WS_UB 33554432ull    // U bf16   [Y][D]       9,135,104 B
#define WS_AB 42689536ull    // alpha bf16 [B][Y][L] 292,323,328 B  (total ~335 MB)

#define GLOAD_LDS16(gsrc, ldst) \
  __builtin_amdgcn_global_load_lds((const __attribute__((address_space(1))) void*)(gsrc), \
                                   (__attribute__((address_space(3))) void*)(ldst), 16, 0, 0)

// ---------------- prep: convert x -> bf16 (both layouts) ----------------
__global__ void prep_x_kernel(const float* __restrict__ x, bf16* __restrict__ xb,
                              bf16* __restrict__ xT)
{
  __shared__ bf16 tile[64][65];
  const int b = blockIdx.z, l0 = blockIdx.x * 64, d0 = blockIdx.y * 64;
  const int t = threadIdx.x;
  const int r = t >> 4, c4 = (t & 15) * 4;
  const float* xp = x + ((size_t)b * L_ + l0) * D_ + d0;
  #pragma unroll
  for (int i = 0; i < 4; i++) {
    int rr = r + i * 16;
    float4 v = *(const float4*)(xp + (size_t)rr * D_ + c4);
    bf16 b0 = (bf16)v.x, b1 = (bf16)v.y, b2 = (bf16)v.z, b3 = (bf16)v.w;
    bf16x4 pk = {b0, b1, b2, b3};
    *(bf16x4*)(xb + ((size_t)b * L_ + l0 + rr) * D_ + d0 + c4) = pk;
    tile[rr][c4 + 0] = b0; tile[rr][c4 + 1] = b1;
    tile[rr][c4 + 2] = b2; tile[rr][c4 + 3] = b3;
  }
  __syncthreads();
  #pragma unroll
  for (int i = 0; i < 4; i++) {
    int dd = r + i * 16;
    bf16x4 pk = {tile[c4 + 0][dd], tile[c4 + 1][dd], tile[c4 + 2][dd], tile[c4 + 3][dd]};
    *(bf16x4*)(xT + ((size_t)b * D_ + d0 + dd) * L_ + l0 + c4) = pk;
  }
}

__global__ void prep_u_kernel(const float* __restrict__ U, bf16* __restrict__ Ub)
{
  size_t i4 = ((size_t)blockIdx.x * 256 + threadIdx.x) * 4;
  if (i4 >= (size_t)Y_ * D_) return;
  float4 v = *(const float4*)(U + i4);
  bf16x4 pk = {(bf16)v.x, (bf16)v.y, (bf16)v.z, (bf16)v.w};
  *(bf16x4*)(Ub + i4) = pk;
}

// ------------- K1: scores = U x^T, softmax over L, write alpha -------------
// block: 32 Y-rows x 2048 L-cols fully resident; 8 waves, wave w owns cols [w*256,w*256+256)
__global__ __launch_bounds__(512, 2) void k1_scores_softmax(
    const bf16* __restrict__ xb, const bf16* __restrict__ Ub,
    float* __restrict__ alphaF, bf16* __restrict__ alphaB)
{
  const int b = blockIdx.y;
  const int y0 = blockIdx.x * 32;
  const int tid = threadIdx.x;
  const int w = tid >> 6, lane = tid & 63;
  const int r15 = lane & 15, koct = lane >> 4;

  const bf16* xB = xb + (size_t)b * (L_ * D_);
  f32x4 acc[2][16];
  #pragma unroll
  for (int mt = 0; mt < 2; mt++)
    #pragma unroll
    for (int nt = 0; nt < 16; nt++) acc[mt][nt] = (f32x4){0.f, 0.f, 0.f, 0.f};

  int yy0 = y0 + r15;      if (yy0 > Y_ - 1) yy0 = Y_ - 1;
  int yy1 = y0 + 16 + r15; if (yy1 > Y_ - 1) yy1 = Y_ - 1;
  const bf16* ap0 = Ub + (size_t)yy0 * D_ + koct * 8;
  const bf16* ap1 = Ub + (size_t)yy1 * D_ + koct * 8;
  const bf16* bp  = xB + (size_t)(w * 256 + r15) * D_ + koct * 8;

  for (int k0 = 0; k0 < D_; k0 += 32) {
    bf16x8 a0 = *(const bf16x8*)(ap0 + k0);
    bf16x8 a1 = *(const bf16x8*)(ap1 + k0);
    #pragma unroll
    for (int nt = 0; nt < 16; nt++) {
      bf16x8 bb = *(const bf16x8*)(bp + (size_t)nt * (16 * D_) + k0);
      acc[0][nt] = MFMA16(a0, bb, acc[0][nt]);
      acc[1][nt] = MFMA16(a1, bb, acc[1][nt]);
    }
  }

  // softmax along L.  acc[mt][nt][q]: row = mt*16 + koct*4 + q, col = w*256 + nt*16 + r15
  __shared__ float red[8][32];
  __shared__ float rowstat[32];

  float rmax[2][4];
  #pragma unroll
  for (int mt = 0; mt < 2; mt++)
    #pragma unroll
    for (int q = 0; q < 4; q++) {
      float m = acc[mt][0][q];
      #pragma unroll
      for (int nt = 1; nt < 16; nt++) m = fmaxf(m, acc[mt][nt][q]);
      #pragma unroll
      for (int off = 1; off < 16; off <<= 1) m = fmaxf(m, __shfl_xor(m, off, 64));
      rmax[mt][q] = m;
    }
  if (r15 == 0) {
    #pragma unroll
    for (int mt = 0; mt < 2; mt++)
      #pragma unroll
      for (int q = 0; q < 4; q++) red[w][mt * 16 + koct * 4 + q] = rmax[mt][q];
  }
  __syncthreads();
  if (tid < 32) {
    float m = red[0][tid];
    #pragma unroll
    for (int ww = 1; ww < 8; ww++) m = fmaxf(m, red[ww][tid]);
    rowstat[tid] = m;
  }
  __syncthreads();

  #pragma unroll
  for (int mt = 0; mt < 2; mt++)
    #pragma unroll
    for (int q = 0; q < 4; q++) {
      float mx = rowstat[mt * 16 + koct * 4 + q];
      float s = 0.f;
      #pragma unroll
      for (int nt = 0; nt < 16; nt++) {
        float p = __expf(acc[mt][nt][q] - mx);
        acc[mt][nt][q] = p;
        s += p;
      }
      #pragma unroll
      for (int off = 1; off < 16; off <<= 1) s += __shfl_xor(s, off, 64);
      if (r15 == 0) red[w][mt * 16 + koct * 4 + q] = s;
    }
  __syncthreads();
  if (tid < 32) {
    float s = 0.f;
    #pragma unroll
    for (int ww = 0; ww < 8; ww++) s += red[ww][tid];
    rowstat[tid] = 1.0f / s;
  }
  __syncthreads();

  #pragma unroll
  for (int mt = 0; mt < 2; mt++) {
    #pragma unroll
    for (int q = 0; q < 4; q++) {
      int row = mt * 16 + koct * 4 + q;
      int yg = y0 + row;
      if (yg >= Y_) continue;
      float inv = rowstat[row];
      float* dstF = alphaF + ((size_t)b * Y_ + yg) * L_ + w * 256 + r15;
      bf16*  dstB = alphaB + ((size_t)b * Y_ + yg) * L_ + w * 256 + r15;
      #pragma unroll
      for (int nt = 0; nt < 16; nt++) {
        float aV = acc[mt][nt][q] * inv;
        dstF[nt * 16] = aV;
        dstB[nt * 16] = (bf16)aV;
      }
    }
  }
}

// ------------- K2: m = alpha @ x  (+ y = <m, FW> + bias, BCE loss) -------------
// block: 128 Y-rows x 512 D-cols (full D); A (alpha) staged in swizzled LDS,
// B (x^T) fragments direct from L2. Double-buffered BK=64.
__global__ __launch_bounds__(512, 2) void k2_m_y_loss(
    const bf16* __restrict__ alphaB, const bf16* __restrict__ xT,
    const float* __restrict__ FW, const float* __restrict__ bias,
    const float* __restrict__ target, float* __restrict__ out)
{
  const int b = blockIdx.y;
  const int y0 = blockIdx.x * 128;
  const int tid = threadIdx.x;
  const int w = tid >> 6, lane = tid & 63;
  const int r15 = lane & 15, koct = lane >> 4;

  __shared__ bf16 At[2][128 * 64];  // 16 KB each, XOR-swizzled: LDS[r][s] = G[r][s^(r&7)]

  f32x4 acc[8][4];
  #pragma unroll
  for (int mt = 0; mt < 8; mt++)
    #pragma unroll
    for (int nt = 0; nt < 4; nt++) acc[mt][nt] = (f32x4){0.f, 0.f, 0.f, 0.f};

  auto stage = [&](int kk, int bufI) {
    #pragma unroll
    for (int rd = 0; rd < 2; rd++) {
      int r = rd * 64 + w * 8 + (lane >> 3);
      int sg = (lane & 7) ^ (lane >> 3);   // (s ^ (r&7)), r&7 == lane>>3 here
      int yg = y0 + r; if (yg > Y_ - 1) yg = Y_ - 1;
      const bf16* src = alphaB + ((size_t)b * Y_ + yg) * L_ + kk * 64 + sg * 8;
      GLOAD_LDS16(src, &At[bufI][rd * 4096 + w * 512]);
    }
  };

  const bf16* bp = xT + ((size_t)b * D_ + w * 64 + r15) * L_ + koct * 8;

  stage(0, 0);
  for (int kk = 0; kk < 32; kk++) {
    __syncthreads();                    // stage(kk) complete; prev reads of buf done
    if (kk + 1 < 32) stage(kk + 1, (kk + 1) & 1);  // overlaps with compute below
    const bf16* At_cur = &At[kk & 1][0];
    const int k0 = kk * 64;
    #pragma unroll
    for (int kh = 0; kh < 2; kh++) {
      bf16x8 bfr[4];
      #pragma unroll
      for (int nt = 0; nt < 4; nt++)
        bfr[nt] = *(const bf16x8*)(bp + (size_t)nt * (16 * L_) + k0 + kh * 32);
      #pragma unroll
      for (int mt = 0; mt < 8; mt++) {
        int r = mt * 16 + r15;
        int slot = (kh * 4 + koct) ^ (r & 7);
        bf16x8 afr = *(const bf16x8*)(At_cur + r * 64 + slot * 8);
        #pragma unroll
        for (int nt = 0; nt < 4; nt++) acc[mt][nt] = MFMA16(afr, bfr[nt], acc[mt][nt]);
      }
    }
  }

  // epilogue: write m, compute y and loss
  // acc[mt][nt][q]: row = mt*16 + koct*4 + q (local y), col = w*64 + nt*16 + r15 (d)
  float ypart[8][4];
  #pragma unroll
  for (int mt = 0; mt < 8; mt++) {
    #pragma unroll
    for (int q = 0; q < 4; q++) {
      int row = mt * 16 + koct * 4 + q;
      int yg = y0 + row;
      bool ok = (yg < Y_);
      int ygc = ok ? yg : (Y_ - 1);
      const float* fw = FW + (size_t)ygc * D_ + w * 64 + r15;
      float* mrow = out + OFF_M + ((size_t)b * Y_ + ygc) * D_ + w * 64 + r15;
      float p = 0.f;
      #pragma unroll
      for (int nt = 0; nt < 4; nt++) {
        float v = acc[mt][nt][q];
        if (ok) mrow[nt * 16] = v;
        p += v * fw[nt * 16];
      }
      ypart[mt][q] = p;
    }
  }
  #pragma unroll
  for (int mt = 0; mt < 8; mt++)
    #pragma unroll
    for (int q = 0; q < 4; q++) {
      float p = ypart[mt][q];
      #pragma unroll
      for (int off = 1; off < 16; off <<= 1) p += __shfl_xor(p, off, 64);
      ypart[mt][q] = p;
    }
  __shared__ float yred[8][128];
  if (r15 == 0) {
    #pragma unroll
    for (int mt = 0; mt < 8; mt++)
      #pragma unroll
      for (int q = 0; q < 4; q++) yred[w][mt * 16 + koct * 4 + q] = ypart[mt][q];
  }
  __syncthreads();
  if (tid < 128) {
    int yg = y0 + tid;
    float s = 0.f;
    #pragma unroll
    for (int ww = 0; ww < 8; ww++) s += yred[ww][tid];
    float lterm = 0.f;
    if (yg < Y_) {
      float yv = s + bias[yg];
      out[(size_t)b * Y_ + yg] = yv;
      float tv = target[(size_t)b * Y_ + yg];
      lterm = fmaxf(yv, 0.f) - yv * tv + log1pf(__expf(-fabsf(yv)));
    }
    #pragma unroll
    for (int off = 1; off < 64; off <<= 1) lterm += __shfl_xor(lterm, off, 64);
    if ((tid & 63) == 0)
      atomicAdd(out + OFF_LOSS, lterm * (1.0f / ((float)B_ * (float)Y_)));
  }
}

extern "C" void kernel_launch(void* const* d_in, const int* in_sizes, int n_in,
                              void* d_out, int out_size, void* d_ws, size_t ws_size,
                              hipStream_t stream) {
  const float* x      = (const float*)d_in[0];
  const float* target = (const float*)d_in[1];
  // d_in[2] text_inputs: unused
  const float* U      = (const float*)d_in[3];
  const float* FW     = (const float*)d_in[4];
  const float* bias   = (const float*)d_in[5];
  float* out = (float*)d_out;

  char* ws = (char*)d_ws;
  bf16* xb = (bf16*)(ws + WS_XB);
  bf16* xT = (bf16*)(ws + WS_XT);
  bf16* Ub = (bf16*)(ws + WS_UB);
  bf16* aB = (bf16*)(ws + WS_AB);

  hipMemsetAsync((char*)d_out + OFF_LOSS * 4, 0, 4, stream);

  prep_x_kernel<<<dim3(L_ / 64, D_ / 64, B_), 256, 0, stream>>>(x, xb, xT);
  prep_u_kernel<<<dim3((Y_ * D_ / 4 + 255) / 256), 256, 0, stream>>>(U, Ub);

  k1_scores_softmax<<<dim3((Y_ + 31) / 32, B_), 512, 0, stream>>>(
      xb, Ub, out + OFF_ALPHA, aB);

  k2_m_y_loss<<<dim3((Y_ + 127) / 128, B_), 512, 0, stream>>>(
      aB, xT, FW, bias, target, out);
}

// Round 3
// 1554.049 us; speedup vs baseline: 1.2062x; 1.2062x over previous
//
#include <hip/hip_runtime.h>
#include <hip/hip_bf16.h>

#define B_ 8
#define L_ 2048
#define D_ 512
#define Y_ 8921
#define YPAD 8960
#define NLT 16

typedef __bf16 bf16;
typedef __attribute__((ext_vector_type(8))) __bf16 bf16x8;
typedef __attribute__((ext_vector_type(4))) __bf16 bf16x4;
typedef __attribute__((ext_vector_type(4))) float f32x4;

#define MFMA16(a,b,c) __builtin_amdgcn_mfma_f32_16x16x32_bf16((a),(b),(c),0,0,0)

// d_out offsets (floats): y[B*Y], loss[1], alpha[B*Y*L], m[B*Y*D]
#define OFF_LOSS  71368ull
#define OFF_ALPHA 71369ull
#define OFF_M     146233033ull

// workspace offsets (bytes)
#define WS_XB 0ull            // x bf16   [B][L][D]      16,777,216
#define WS_XT 16777216ull     // x^T bf16 [B][D][L]      16,777,216
#define WS_UB 33554432ull     // U bf16   [YPAD][D]       9,175,040
#define WS_P  42729472ull     // P bf16   [B][YPAD][L] 293,601,280
#define WS_PM 336330752ull    // part max [B][NLT][YPAD]  4,587,520
#define WS_PS 340918272ull    // part sum [B][NLT][YPAD]  4,587,520
#define WS_SC 345505792ull    // scale    [B][NLT][YPAD]  4,587,520
#define WS_YP 350093312ull    // y partial[B][2][YPAD]      573,440

#define GLOAD_LDS16(gsrc, ldst) \
  __builtin_amdgcn_global_load_lds((const __attribute__((address_space(1))) void*)(gsrc), \
                                   (__attribute__((address_space(3))) void*)(ldst), 16, 0, 0)

// ---------------- prep: x -> bf16 (both layouts) ----------------
__global__ void prep_x_kernel(const float* __restrict__ x, bf16* __restrict__ xb,
                              bf16* __restrict__ xT)
{
  __shared__ bf16 tile[64][65];
  const int b = blockIdx.z, l0 = blockIdx.x * 64, d0 = blockIdx.y * 64;
  const int t = threadIdx.x;
  const int r = t >> 4, c4 = (t & 15) * 4;
  const float* xp = x + ((size_t)b * L_ + l0) * D_ + d0;
  #pragma unroll
  for (int i = 0; i < 4; i++) {
    int rr = r + i * 16;
    float4 v = *(const float4*)(xp + (size_t)rr * D_ + c4);
    bf16 b0 = (bf16)v.x, b1 = (bf16)v.y, b2 = (bf16)v.z, b3 = (bf16)v.w;
    bf16x4 pk = {b0, b1, b2, b3};
    *(bf16x4*)(xb + ((size_t)b * L_ + l0 + rr) * D_ + d0 + c4) = pk;
    tile[rr][c4 + 0] = b0; tile[rr][c4 + 1] = b1;
    tile[rr][c4 + 2] = b2; tile[rr][c4 + 3] = b3;
  }
  __syncthreads();
  #pragma unroll
  for (int i = 0; i < 4; i++) {
    int dd = r + i * 16;
    bf16x4 pk = {tile[c4 + 0][dd], tile[c4 + 1][dd], tile[c4 + 2][dd], tile[c4 + 3][dd]};
    *(bf16x4*)(xT + ((size_t)b * D_ + d0 + dd) * L_ + l0 + c4) = pk;
  }
}

__global__ void prep_u_kernel(const float* __restrict__ U, bf16* __restrict__ Ub)
{
  size_t i4 = ((size_t)blockIdx.x * 256 + threadIdx.x) * 4;
  if (i4 >= (size_t)YPAD * D_) return;
  int r = (int)(i4 >> 9);
  int c = (int)(i4 & 511);
  int rs = r < Y_ ? r : (Y_ - 1);
  float4 v = *(const float4*)(U + (size_t)rs * D_ + c);
  bf16x4 pk = {(bf16)v.x, (bf16)v.y, (bf16)v.z, (bf16)v.w};
  *(bf16x4*)(Ub + i4) = pk;
}

// ------- K1: scores GEMM tile (128Yx128L, K=512) -> P=exp(s-tilemax) bf16 + partials -------
__global__ __launch_bounds__(512, 4) void k1_gemm_pexp(
    const bf16* __restrict__ xb, const bf16* __restrict__ Ub,
    bf16* __restrict__ P, float* __restrict__ pmax, float* __restrict__ psum)
{
  const int yt = blockIdx.x, lt = blockIdx.y, b = blockIdx.z;
  const int y0 = yt * 128, l0 = lt * 128;
  const int tid = threadIdx.x;
  const int w = tid >> 6, lane = tid & 63;
  const int wr = w >> 2, wc = w & 3;              // 2 x 4 waves, wave-tile 64x32
  const int r15 = lane & 15, koct = lane >> 4;

  __shared__ bf16 As[2][128 * 64];
  __shared__ bf16 Bs[2][128 * 64];
  __shared__ float redm[2][64][4];
  __shared__ float reds[2][64][4];

  f32x4 acc[4][2];
  #pragma unroll
  for (int mt = 0; mt < 4; mt++)
    #pragma unroll
    for (int nt = 0; nt < 2; nt++) acc[mt][nt] = (f32x4){0.f, 0.f, 0.f, 0.f};

  const bf16* xB = xb + (size_t)b * (L_ * D_);
  const int srow = (lane >> 3), scol = (lane & 7) * 8;

  auto stage = [&](int kk, int bufI) {
    #pragma unroll
    for (int i = 0; i < 2; i++) {
      int c = w * 2 + i;
      int row = c * 8 + srow;
      GLOAD_LDS16(Ub + (size_t)(y0 + row) * D_ + kk * 64 + scol, &As[bufI][c * 512]);
      GLOAD_LDS16(xB + (size_t)(l0 + row) * D_ + kk * 64 + scol, &Bs[bufI][c * 512]);
    }
  };

  stage(0, 0);
  for (int kk = 0; kk < 8; kk++) {
    __syncthreads();
    if (kk < 7) stage(kk + 1, (kk + 1) & 1);
    const bf16* Ac = As[kk & 1];
    const bf16* Bc = Bs[kk & 1];
    #pragma unroll
    for (int kh = 0; kh < 2; kh++) {
      bf16x8 af[4], bfr[2];
      #pragma unroll
      for (int mt = 0; mt < 4; mt++)
        af[mt] = *(const bf16x8*)(Ac + (wr * 64 + mt * 16 + r15) * 64 + kh * 32 + koct * 8);
      #pragma unroll
      for (int nt = 0; nt < 2; nt++)
        bfr[nt] = *(const bf16x8*)(Bc + (wc * 32 + nt * 16 + r15) * 64 + kh * 32 + koct * 8);
      #pragma unroll
      for (int mt = 0; mt < 4; mt++)
        #pragma unroll
        for (int nt = 0; nt < 2; nt++)
          acc[mt][nt] = MFMA16(af[mt], bfr[nt], acc[mt][nt]);
    }
  }

  // epilogue: per-row (of 128-col tile) max, P = exp(s - max), sum
  // acc[mt][nt][q]: local row = wr*64+mt*16+koct*4+q, local col = wc*32+nt*16+r15
  #pragma unroll
  for (int mt = 0; mt < 4; mt++)
    #pragma unroll
    for (int q = 0; q < 4; q++) {
      float m = fmaxf(acc[mt][0][q], acc[mt][1][q]);
      #pragma unroll
      for (int off = 1; off < 16; off <<= 1) m = fmaxf(m, __shfl_xor(m, off, 64));
      if (r15 == 0) redm[wr][mt * 16 + koct * 4 + q][wc] = m;
    }
  __syncthreads();
  #pragma unroll
  for (int mt = 0; mt < 4; mt++)
    #pragma unroll
    for (int q = 0; q < 4; q++) {
      int r64 = mt * 16 + koct * 4 + q;
      float M4 = fmaxf(fmaxf(redm[wr][r64][0], redm[wr][r64][1]),
                       fmaxf(redm[wr][r64][2], redm[wr][r64][3]));
      int grow = y0 + wr * 64 + r64;
      bf16* dst = P + ((size_t)b * YPAD + grow) * L_ + l0 + wc * 32 + r15;
      float s = 0.f;
      #pragma unroll
      for (int nt = 0; nt < 2; nt++) {
        float p = __expf(acc[mt][nt][q] - M4);
        dst[nt * 16] = (bf16)p;
        s += p;
      }
      #pragma unroll
      for (int off = 1; off < 16; off <<= 1) s += __shfl_xor(s, off, 64);
      if (r15 == 0) reds[wr][r64][wc] = s;
    }
  __syncthreads();
  if (tid < 128) {
    int wr2 = tid >> 6, r64 = tid & 63;
    float M = fmaxf(fmaxf(redm[wr2][r64][0], redm[wr2][r64][1]),
                    fmaxf(redm[wr2][r64][2], redm[wr2][r64][3]));
    float S = reds[wr2][r64][0] + reds[wr2][r64][1] + reds[wr2][r64][2] + reds[wr2][r64][3];
    size_t idx = ((size_t)b * NLT + lt) * YPAD + y0 + tid;
    pmax[idx] = M;
    psum[idx] = S;
  }
}

// ------- K1b: combine partials -> scale[b][lt][y] = exp(max_p - M)/S -------
__global__ void k1b_scale(const float* __restrict__ pmax, const float* __restrict__ psum,
                          float* __restrict__ scale)
{
  const int b = blockIdx.y;
  const int y = blockIdx.x * 256 + threadIdx.x;   // < YPAD
  float pm[NLT];
  float M = -1e30f;
  #pragma unroll
  for (int lt = 0; lt < NLT; lt++) {
    pm[lt] = pmax[((size_t)b * NLT + lt) * YPAD + y];
    M = fmaxf(M, pm[lt]);
  }
  float S = 0.f;
  #pragma unroll
  for (int lt = 0; lt < NLT; lt++)
    S += psum[((size_t)b * NLT + lt) * YPAD + y] * __expf(pm[lt] - M);
  float inv = 1.0f / S;
  #pragma unroll
  for (int lt = 0; lt < NLT; lt++)
    scale[((size_t)b * NLT + lt) * YPAD + y] = __expf(pm[lt] - M) * inv;
}

// ------- K2: m = alpha @ x (alpha = P*scale, emitted f32 on the fly) + y partials -------
__global__ __launch_bounds__(512, 4) void k2_m_y(
    const bf16* __restrict__ P, const bf16* __restrict__ xT,
    const float* __restrict__ scale, const float* __restrict__ FW,
    float* __restrict__ out, float* __restrict__ yp)
{
  const int yt = blockIdx.x, dh = blockIdx.y, b = blockIdx.z;
  const int y0 = yt * 128, d0 = dh * 256;
  const int tid = threadIdx.x;
  const int w = tid >> 6, lane = tid & 63;
  const int wr = w >> 2, wc = w & 3;              // 2 x 4 waves, wave-tile 64x64
  const int r15 = lane & 15, koct = lane >> 4;

  __shared__ bf16 As[2][128 * 32];
  __shared__ bf16 Bs[2][256 * 32];
  __shared__ float scl[NLT * 128];
  __shared__ float yred[128][4];

  for (int i = tid; i < NLT * 128; i += 512) {
    int lt2 = i >> 7, r = i & 127;
    scl[i] = scale[((size_t)b * NLT + lt2) * YPAD + y0 + r];
  }

  f32x4 acc[4][4];
  #pragma unroll
  for (int mt = 0; mt < 4; mt++)
    #pragma unroll
    for (int nt = 0; nt < 4; nt++) acc[mt][nt] = (f32x4){0.f, 0.f, 0.f, 0.f};

  const int ar = tid >> 2, akc = (tid & 3) * 8;
  const bf16* aps = P + ((size_t)b * YPAD + y0 + ar) * L_ + akc;
  float* afs = out + OFF_ALPHA + ((size_t)b * Y_ + y0 + ar) * (size_t)L_ + akc;
  const bool awrite = (dh == 0) && (y0 + ar < Y_);

  auto writeA = [&](int kk, int bufI, bf16x8 pv) {
    float s = scl[(kk >> 2) * 128 + ar];
    float a[8];
    #pragma unroll
    for (int j = 0; j < 8; j++) a[j] = (float)pv[j] * s;
    if (awrite) {
      #pragma unroll
      for (int j = 0; j < 8; j++) afs[(size_t)kk * 32 + j] = a[j];
    }
    bf16x8 ab;
    #pragma unroll
    for (int j = 0; j < 8; j++) ab[j] = (bf16)a[j];
    *(bf16x8*)(&As[bufI][ar * 32 + akc]) = ab;
  };
  const int brow = (lane >> 2), bcol = (lane & 3) * 8;
  auto stageB = [&](int kk, int bufI) {
    #pragma unroll
    for (int i = 0; i < 2; i++) {
      int c = w * 2 + i;
      int row = c * 16 + brow;
      GLOAD_LDS16(xT + ((size_t)b * D_ + d0 + row) * L_ + kk * 32 + bcol, &Bs[bufI][c * 512]);
    }
  };

  __syncthreads();   // scl visible to all
  {
    bf16x8 pv0 = *(const bf16x8*)(aps);
    stageB(0, 0);
    writeA(0, 0, pv0);
  }

  for (int kk = 0; kk < 64; kk++) {
    __syncthreads();
    bf16x8 pv;
    if (kk < 63) {
      pv = *(const bf16x8*)(aps + (size_t)(kk + 1) * 32);   // issue early (T14)
      stageB(kk + 1, (kk + 1) & 1);
    }
    const bf16* Ac = As[kk & 1];
    const bf16* Bc = Bs[kk & 1];
    bf16x8 af[4], bfr[4];
    #pragma unroll
    for (int mt = 0; mt < 4; mt++)
      af[mt] = *(const bf16x8*)(Ac + (wr * 64 + mt * 16 + r15) * 32 + koct * 8);
    #pragma unroll
    for (int nt = 0; nt < 4; nt++)
      bfr[nt] = *(const bf16x8*)(Bc + (wc * 64 + nt * 16 + r15) * 32 + koct * 8);
    #pragma unroll
    for (int mt = 0; mt < 4; mt++)
      #pragma unroll
      for (int nt = 0; nt < 4; nt++)
        acc[mt][nt] = MFMA16(af[mt], bfr[nt], acc[mt][nt]);
    if (kk < 63) writeA(kk + 1, (kk + 1) & 1, pv);          // write late (T14)
  }

  // epilogue: m writes + y partial over this D-half
  #pragma unroll
  for (int mt = 0; mt < 4; mt++)
    #pragma unroll
    for (int q = 0; q < 4; q++) {
      int row = wr * 64 + mt * 16 + koct * 4 + q;
      int yg = y0 + row;
      bool ok = (yg < Y_);
      int ygc = ok ? yg : (Y_ - 1);
      const float* fw = FW + (size_t)ygc * D_ + d0 + wc * 64 + r15;
      float* mrow = out + OFF_M + ((size_t)b * Y_ + ygc) * D_ + d0 + wc * 64 + r15;
      float p = 0.f;
      #pragma unroll
      for (int nt = 0; nt < 4; nt++) {
        float v = acc[mt][nt][q];
        if (ok) mrow[nt * 16] = v;
        p += v * fw[nt * 16];
      }
      #pragma unroll
      for (int off = 1; off < 16; off <<= 1) p += __shfl_xor(p, off, 64);
      if (r15 == 0) yred[row][wc] = p;
    }
  __syncthreads();
  if (tid < 128) {
    float s = yred[tid][0] + yred[tid][1] + yred[tid][2] + yred[tid][3];
    yp[((size_t)b * 2 + dh) * YPAD + y0 + tid] = s;
  }
}

// ------- K3: y = sum halves + bias; BCE loss -------
__global__ void k3_y_loss(const float* __restrict__ yp, const float* __restrict__ bias,
                          const float* __restrict__ target, float* __restrict__ out)
{
  const int b = blockIdx.y;
  const int y = blockIdx.x * 256 + threadIdx.x;
  float lterm = 0.f;
  if (y < Y_) {
    float v = yp[((size_t)b * 2) * YPAD + y] + yp[((size_t)b * 2 + 1) * YPAD + y] + bias[y];
    out[(size_t)b * Y_ + y] = v;
    float t = target[(size_t)b * Y_ + y];
    lterm = fmaxf(v, 0.f) - v * t + log1pf(__expf(-fabsf(v)));
  }
  #pragma unroll
  for (int off = 1; off < 64; off <<= 1) lterm += __shfl_xor(lterm, off, 64);
  __shared__ float lred[4];
  if ((threadIdx.x & 63) == 0) lred[threadIdx.x >> 6] = lterm;
  __syncthreads();
  if (threadIdx.x == 0)
    atomicAdd(out + OFF_LOSS,
              (lred[0] + lred[1] + lred[2] + lred[3]) * (1.0f / ((float)B_ * (float)Y_)));
}

extern "C" void kernel_launch(void* const* d_in, const int* in_sizes, int n_in,
                              void* d_out, int out_size, void* d_ws, size_t ws_size,
                              hipStream_t stream) {
  const float* x      = (const float*)d_in[0];
  const float* target = (const float*)d_in[1];
  const float* U      = (const float*)d_in[3];
  const float* FW     = (const float*)d_in[4];
  const float* bias   = (const float*)d_in[5];
  float* out = (float*)d_out;

  char* ws = (char*)d_ws;
  bf16* xb = (bf16*)(ws + WS_XB);
  bf16* xT = (bf16*)(ws + WS_XT);
  bf16* Ub = (bf16*)(ws + WS_UB);
  bf16* P  = (bf16*)(ws + WS_P);
  float* pm = (float*)(ws + WS_PM);
  float* ps = (float*)(ws + WS_PS);
  float* sc = (float*)(ws + WS_SC);
  float* yp = (float*)(ws + WS_YP);

  hipMemsetAsync((char*)d_out + OFF_LOSS * 4, 0, 4, stream);

  prep_x_kernel<<<dim3(L_ / 64, D_ / 64, B_), 256, 0, stream>>>(x, xb, xT);
  prep_u_kernel<<<dim3((YPAD * D_ / 4 + 255) / 256), 256, 0, stream>>>(U, Ub);

  k1_gemm_pexp<<<dim3(YPAD / 128, NLT, B_), 512, 0, stream>>>(xb, Ub, P, pm, ps);
  k1b_scale<<<dim3(YPAD / 256, B_), 256, 0, stream>>>(pm, ps, sc);
  k2_m_y<<<dim3(YPAD / 128, 2, B_), 512, 0, stream>>>(P, xT, sc, FW, out, yp);
  k3_y_loss<<<dim3(YPAD / 256, B_), 256, 0, stream>>>(yp, bias, target, out);
}